// Round 8
// baseline (868.855 us; speedup 1.0000x reference)
//
#include <hip/hip_runtime.h>
#include <stdint.h>

#define BDIM 4096
#define HDIM 2048
#define VDIM 32000
#define HALF (BDIM / 2)
#define IGNORE_INDEX (-100)

typedef int   v8i  __attribute__((ext_vector_type(8)));
typedef int   v4i  __attribute__((ext_vector_type(4)));
typedef float v16f __attribute__((ext_vector_type(16)));
typedef float f32x4 __attribute__((ext_vector_type(4)));
typedef __bf16 bf16x8 __attribute__((ext_vector_type(8)));

#define AS1 __attribute__((address_space(1)))
#define AS3 __attribute__((address_space(3)))

__device__ __forceinline__ unsigned short f2bf(float f) {
    union { float f; unsigned int u; } v; v.f = f;
    unsigned int u = v.u;
    unsigned int r = u + 0x7FFFu + ((u >> 16) & 1u);
    return (unsigned short)(r >> 16);
}

// fp32 -> fp8(e4m3, OCP) conversion for x (scale 1) and W (pre-scale by 64:
// W ~ U(+-0.022) is subnormal in e4m3; x64 moves it into the normal range.
// The GEMM epilogue multiplies accumulators by 2^-6 (exact).
// UNCHANGED from round 7 (single-variable discipline: this round edits only
// the gemm schedule).
__global__ void cvt_fp8_kernel(const float* __restrict__ x,
                               const float* __restrict__ W,
                               uint8_t* __restrict__ xq,
                               uint8_t* __restrict__ wq,
                               int nx4, int ntot4) {
    const int nth = gridDim.x * blockDim.x;
    const int t = blockIdx.x * blockDim.x + threadIdx.x;
    const int i0 = ((t >> 6) << 8) + (t & 63);
    const int stride = nth * 4;
    for (int i = i0; i < ntot4; i += stride) {
        const float4* s; unsigned* d; int j; float m;
        if (i < nx4) { s = (const float4*)x; d = (unsigned*)xq; j = i; m = 1.0f; }
        else         { s = (const float4*)W; d = (unsigned*)wq; j = i - nx4; m = 64.0f; }
        float4 f0 = s[j];
        float4 f1 = s[j + 64];
        float4 f2 = s[j + 128];
        float4 f3 = s[j + 192];
        int w;
        w = __builtin_amdgcn_cvt_pk_fp8_f32(f0.x * m, f0.y * m, 0, false);
        w = __builtin_amdgcn_cvt_pk_fp8_f32(f0.z * m, f0.w * m, w, true);
        d[j] = (unsigned)w;
        w = __builtin_amdgcn_cvt_pk_fp8_f32(f1.x * m, f1.y * m, 0, false);
        w = __builtin_amdgcn_cvt_pk_fp8_f32(f1.z * m, f1.w * m, w, true);
        d[j + 64] = (unsigned)w;
        w = __builtin_amdgcn_cvt_pk_fp8_f32(f2.x * m, f2.y * m, 0, false);
        w = __builtin_amdgcn_cvt_pk_fp8_f32(f2.z * m, f2.w * m, w, true);
        d[j + 128] = (unsigned)w;
        w = __builtin_amdgcn_cvt_pk_fp8_f32(f3.x * m, f3.y * m, 0, false);
        w = __builtin_amdgcn_cvt_pk_fp8_f32(f3.z * m, f3.w * m, w, true);
        d[j + 192] = (unsigned)w;
    }
}

// Fused fp8 GEMM (x @ W^T) + per-row {sum exp, sum, target-logit}.
// 128x128 tile, 4 waves in 2x2 quadrants, 2x2 tiles of
// mfma_scale_f32_32x32x64_f8f6f4 per 64-wide k-slice.
//
// ROUND-8 SCHEDULE (T3/T4 minimum 2-phase, counted vmcnt):
//   prologue: STAGE(buf0, slice0)
//   per slice: STAGE(buf^1, next) -> s_waitcnt vmcnt(4) (own prev 4 loads
//   done; NEVER drain to 0 in the loop) -> raw s_barrier -> ds_read + 4 MFMA
//   (setprio 1) -> raw s_barrier.
// __syncthreads() is NOT used in the K-loop: it would emit a full
// vmcnt(0) drain and kill the prefetch overlap (this was the round-7
// bottleneck: MfmaUtil 26%, HBM 10%, stage latency exposed per K-step).
// Race audit: each wave verifies ITS OWN 4 loads via vmcnt(4) before
// barrier#1, so after barrier#1 all waves' stages of the read-buffer are
// complete. Barrier#2 (after MFMA issue; ds_reads consumed into regs by
// then) orders reads of buf[cur] before the next iteration's stage
// overwrites it. All control flow is block-uniform.
//
// LDS swizzle (unchanged math, verified passing): 16-B chunk c of row r
// stored at sigma_r(c) = (c + ((r>>1)&3)) & 3; staging permutes the GLOBAL
// source chunk so global_load_lds keeps its contiguous lane*16 mapping.
// (Round-7 PMC: residual conflicts 3.3e7 cyc = 0.01% of dispatch — immaterial.)
__global__ __launch_bounds__(256, 4)
void gemm_reduce_fp8(const uint8_t* __restrict__ A, const uint8_t* __restrict__ B,
                     const int* __restrict__ y,
                     float* __restrict__ sumexp, float* __restrict__ sumlog,
                     float* __restrict__ tlog) {
    __shared__ uint8_t sA[2][128 * 64];
    __shared__ uint8_t sB[2][128 * 64];

    const int tid = threadIdx.x;
    const int lane = tid & 63;
    const int wave = tid >> 6;
    const int wm = wave >> 1, wn = wave & 1;
    const int m0 = blockIdx.x * 128;
    const int v0 = blockIdx.y * 128;

    v16f acc[2][2];
#pragma unroll
    for (int i = 0; i < 2; i++)
#pragma unroll
        for (int j = 0; j < 2; j++)
#pragma unroll
            for (int r = 0; r < 16; r++) acc[i][j][r] = 0.f;

    // Staging: wave stages rows [wave*32, wave*32+32) of sA and sB, 16 rows
    // per global_load_lds (64 lanes x 16 B). Lane l -> LDS row (l>>2), chunk
    // position p = l&3; source chunk c = (p - ((R>>1)&3)) & 3. With
    // R = wave*32 (+16) + (l>>2), (R>>1)&3 = (l>>3)&3 for both row halves.
    const int srow = wave * 32 + (lane >> 2);
    const int sc   = ((lane & 3) - ((lane >> 3) & 3)) & 3;
    const uint8_t* gA0 = A + (size_t)(m0 + srow) * HDIM + sc * 16;
    const uint8_t* gB0 = B + (size_t)(v0 + srow) * HDIM + sc * 16;
    const uint8_t* gA1 = gA0 + (size_t)16 * HDIM;
    const uint8_t* gB1 = gB0 + (size_t)16 * HDIM;
    const int lofs0 = (wave * 32) * 64;
    const int lofs1 = lofs0 + 16 * 64;

    // Fragment reads (per lane): row l&31 of the 32-row tile, k-half h=l>>5
    // -> source chunks 2h, 2h+1 at swizzled positions.
    const int fr32 = lane & 31;
    const int h = lane >> 5;
    const int swr = (fr32 >> 1) & 3;
    const int pos0 = (2 * h + swr) & 3;
    const int pos1 = (2 * h + 1 + swr) & 3;
    const int rA0 = (wm * 64 + fr32) * 64;
    const int rA1 = (wm * 64 + 32 + fr32) * 64;
    const int rB0 = (wn * 64 + fr32) * 64;
    const int rB1 = (wn * 64 + 32 + fr32) * 64;

    // 4 global_load_lds per wave per slice (1 KB each).
#define STAGE(BUF, KT) do {                                                     \
        __builtin_amdgcn_global_load_lds(                                       \
            (const AS1 unsigned int*)(gA0 + (size_t)(KT) * 64),                 \
            (AS3 unsigned int*)(&sA[BUF][lofs0]), 16, 0, 0);                    \
        __builtin_amdgcn_global_load_lds(                                       \
            (const AS1 unsigned int*)(gA1 + (size_t)(KT) * 64),                 \
            (AS3 unsigned int*)(&sA[BUF][lofs1]), 16, 0, 0);                    \
        __builtin_amdgcn_global_load_lds(                                       \
            (const AS1 unsigned int*)(gB0 + (size_t)(KT) * 64),                 \
            (AS3 unsigned int*)(&sB[BUF][lofs0]), 16, 0, 0);                    \
        __builtin_amdgcn_global_load_lds(                                       \
            (const AS1 unsigned int*)(gB1 + (size_t)(KT) * 64),                 \
            (AS3 unsigned int*)(&sB[BUF][lofs1]), 16, 0, 0);                    \
    } while (0)

#define KSTEP(BUF, VMASM) do {                                                  \
        asm volatile(VMASM ::: "memory");                                       \
        __builtin_amdgcn_sched_barrier(0);                                      \
        __builtin_amdgcn_s_barrier();                                           \
        const v4i* pA0 = (const v4i*)&sA[BUF][rA0];                             \
        const v4i* pA1 = (const v4i*)&sA[BUF][rA1];                             \
        const v4i* pB0 = (const v4i*)&sB[BUF][rB0];                             \
        const v4i* pB1 = (const v4i*)&sB[BUF][rB1];                             \
        v4i a00 = pA0[pos0], a01 = pA0[pos1];                                   \
        v4i a10 = pA1[pos0], a11 = pA1[pos1];                                   \
        v4i b00 = pB0[pos0], b01 = pB0[pos1];                                   \
        v4i b10 = pB1[pos0], b11 = pB1[pos1];                                   \
        v8i af0 = {a00[0], a00[1], a00[2], a00[3], a01[0], a01[1], a01[2], a01[3]}; \
        v8i af1 = {a10[0], a10[1], a10[2], a10[3], a11[0], a11[1], a11[2], a11[3]}; \
        v8i bf0 = {b00[0], b00[1], b00[2], b00[3], b01[0], b01[1], b01[2], b01[3]}; \
        v8i bf1 = {b10[0], b10[1], b10[2], b10[3], b11[0], b11[1], b11[2], b11[3]}; \
        __builtin_amdgcn_s_setprio(1);                                          \
        acc[0][0] = __builtin_amdgcn_mfma_scale_f32_32x32x64_f8f6f4(            \
            af0, bf0, acc[0][0], 0, 0, 0, 0x7F7F7F7F, 0, 0x7F7F7F7F);           \
        acc[0][1] = __builtin_amdgcn_mfma_scale_f32_32x32x64_f8f6f4(            \
            af0, bf1, acc[0][1], 0, 0, 0, 0x7F7F7F7F, 0, 0x7F7F7F7F);           \
        acc[1][0] = __builtin_amdgcn_mfma_scale_f32_32x32x64_f8f6f4(            \
            af1, bf0, acc[1][0], 0, 0, 0, 0x7F7F7F7F, 0, 0x7F7F7F7F);           \
        acc[1][1] = __builtin_amdgcn_mfma_scale_f32_32x32x64_f8f6f4(            \
            af1, bf1, acc[1][1], 0, 0, 0, 0x7F7F7F7F, 0, 0x7F7F7F7F);           \
        __builtin_amdgcn_s_setprio(0);                                          \
        __builtin_amdgcn_s_barrier();                                           \
    } while (0)

    // 32 k-slices of 64. Static double-buffer indices (rule #20: no
    // runtime-indexed buffers), 2x-unrolled loop, peeled head/tail.
    STAGE(0, 0);
    for (int kt = 0; kt < 30; kt += 2) {
        STAGE(1, kt + 1);
        KSTEP(0, "s_waitcnt vmcnt(4)");
        STAGE(0, kt + 2);
        KSTEP(1, "s_waitcnt vmcnt(4)");
    }
    STAGE(1, 31);
    KSTEP(0, "s_waitcnt vmcnt(4)");
    KSTEP(1, "s_waitcnt vmcnt(0)");

#undef STAGE
#undef KSTEP

    // Epilogue. 32x32 C/D layout: col = lane&31, row = (reg&3)+8*(reg>>2)+4*h.
    // Undo the W x64 pre-scale (exact).
    const float s64 = 0.015625f;
#pragma unroll
    for (int mi = 0; mi < 2; mi++) {
        const int baseRow = m0 + wm * 64 + mi * 32;
#pragma unroll
        for (int reg = 0; reg < 16; reg++) {
            float va = acc[mi][0][reg] * s64;
            float vb = acc[mi][1][reg] * s64;
            float e = __expf(va) + __expf(vb);
            float sm = va + vb;
#pragma unroll
            for (int off = 1; off < 32; off <<= 1) {
                e  += __shfl_xor(e, off);
                sm += __shfl_xor(sm, off);
            }
            int row = baseRow + (reg & 3) + 8 * (reg >> 2) + 4 * h;
            if (fr32 == 0) {
                atomicAdd(&sumexp[row], e);
                atomicAdd(&sumlog[row], sm);
            }
            int yv = y[row];
            int c0 = v0 + wn * 64 + fr32;
            if (c0 == yv) tlog[row] = va;
            if (c0 + 32 == yv) tlog[row] = vb;
        }
    }
}

// Fallback (small ws): fp32 inputs, in-kernel bf16 convert, 16x16x32 path.
__global__ __launch_bounds__(256, 4)
void gemm_reduce_f32(const float* __restrict__ A, const float* __restrict__ B,
                     const int* __restrict__ y,
                     float* __restrict__ sumexp, float* __restrict__ sumlog,
                     float* __restrict__ tlog) {
    __shared__ unsigned short sA[128 * 32];
    __shared__ unsigned short sB[128 * 32];

    const int tid  = threadIdx.x;
    const int lane = tid & 63;
    const int wave = tid >> 6;
    const int wm = wave >> 1, wn = wave & 1;
    const int m0 = blockIdx.x * 128;
    const int v0 = blockIdx.y * 128;
    const int fr = lane & 15;
    const int fq = lane >> 4;
    const int swz = (fr >> 1) & 3;

    f32x4 acc[4][4];
#pragma unroll
    for (int i = 0; i < 4; i++)
#pragma unroll
        for (int j = 0; j < 4; j++) acc[i][j] = (f32x4){0.f, 0.f, 0.f, 0.f};

    const int r8 = tid >> 3;
    const int kc = (tid & 7) * 4;
    for (int kt = 0; kt < HDIM; kt += 32) {
#pragma unroll
        for (int p = 0; p < 4; p++) {
            int row = p * 32 + r8;
            int pos = ((kc >> 3) ^ ((row >> 1) & 3)) * 8 + (kc & 7);
            float4 fa = *(const float4*)&A[(size_t)(m0 + row) * HDIM + kt + kc];
            float4 fb = *(const float4*)&B[(size_t)(v0 + row) * HDIM + kt + kc];
            ushort4 ua, ub;
            ua.x = f2bf(fa.x); ua.y = f2bf(fa.y); ua.z = f2bf(fa.z); ua.w = f2bf(fa.w);
            ub.x = f2bf(fb.x); ub.y = f2bf(fb.y); ub.z = f2bf(fb.z); ub.w = f2bf(fb.w);
            *(ushort4*)&sA[row * 32 + pos] = ua;
            *(ushort4*)&sB[row * 32 + pos] = ub;
        }
        __syncthreads();

        bf16x8 af[4], bf[4];
#pragma unroll
        for (int i = 0; i < 4; i++) {
            af[i] = *(const bf16x8*)&sA[(wm * 64 + i * 16 + fr) * 32 + (fq ^ swz) * 8];
            bf[i] = *(const bf16x8*)&sB[(wn * 64 + i * 16 + fr) * 32 + (fq ^ swz) * 8];
        }
#pragma unroll
        for (int mi = 0; mi < 4; mi++)
#pragma unroll
            for (int ni = 0; ni < 4; ni++)
                acc[mi][ni] = __builtin_amdgcn_mfma_f32_16x16x32_bf16(
                    af[mi], bf[ni], acc[mi][ni], 0, 0, 0);
        __syncthreads();
    }

    const int baseRow = m0 + wm * 64;
    const int cbase = v0 + wn * 64 + fr;
#pragma unroll
    for (int mi = 0; mi < 4; mi++) {
        float se[4] = {0.f, 0.f, 0.f, 0.f};
        float sl[4] = {0.f, 0.f, 0.f, 0.f};
#pragma unroll
        for (int ni = 0; ni < 4; ni++)
#pragma unroll
            for (int r = 0; r < 4; r++) {
                float v = acc[mi][ni][r];
                se[r] += __expf(v);
                sl[r] += v;
            }
#pragma unroll
        for (int r = 0; r < 4; r++) {
            float e = se[r], s = sl[r];
#pragma unroll
            for (int off = 1; off < 16; off <<= 1) {
                e += __shfl_xor(e, off);
                s += __shfl_xor(s, off);
            }
            int row = baseRow + mi * 16 + fq * 4 + r;
            if (fr == 0) {
                atomicAdd(&sumexp[row], e);
                atomicAdd(&sumlog[row], s);
            }
            int yv = y[row];
#pragma unroll
            for (int ni = 0; ni < 4; ni++)
                if (cbase + ni * 16 == yv) tlog[row] = acc[mi][ni][r];
        }
    }
}

// Final scalar loss from per-row stats. One block.
__global__ void finalize_kernel(const float* __restrict__ sumexp,
                                const float* __restrict__ sumlog,
                                const float* __restrict__ tlog,
                                const int* __restrict__ y,
                                float* __restrict__ out) {
    __shared__ float red[3][4];
    float s_nll = 0.f, s_or = 0.f, cnt = 0.f;
    for (int p = threadIdx.x; p < HALF; p += blockDim.x) {
        float lse_c = logf(sumexp[p]);
        float lse_r = logf(sumexp[p + HALF]);
        float mc = sumlog[p] * (1.0f / VDIM);
        float mr = sumlog[p + HALF] * (1.0f / VDIM);
        int yv = y[p];
        if (yv != IGNORE_INDEX) { s_nll += lse_c - tlog[p]; cnt += 1.f; }
        float ch = mc - lse_c, rj = mr - lse_r;
        float lo = (ch - rj) - (log1pf(-expf(ch)) - log1pf(-expf(rj)));
        float ls = fminf(lo, 0.f) - log1pf(expf(-fabsf(lo)));
        s_or += 0.1f * ls;
    }
    for (int off = 32; off; off >>= 1) {
        s_nll += __shfl_down(s_nll, off);
        s_or  += __shfl_down(s_or, off);
        cnt   += __shfl_down(cnt, off);
    }
    int wave = threadIdx.x >> 6, lane = threadIdx.x & 63;
    if (lane == 0) { red[0][wave] = s_nll; red[1][wave] = s_or; red[2][wave] = cnt; }
    __syncthreads();
    if (threadIdx.x == 0) {
        float tn = 0.f, to = 0.f, tc = 0.f;
        for (int w = 0; w < 4; w++) { tn += red[0][w]; to += red[1][w]; tc += red[2][w]; }
        out[0] = tn / fmaxf(tc, 1.f) - to / (float)HALF;
    }
}

extern "C" void kernel_launch(void* const* d_in, const int* in_sizes, int n_in,
                              void* d_out, int out_size, void* d_ws, size_t ws_size,
                              hipStream_t stream) {
    const float* x = (const float*)d_in[0];
    const float* W = (const float*)d_in[1];
    const int* y   = (const int*)d_in[2];
    float* out     = (float*)d_out;

    float* sumexp = (float*)d_ws;
    float* sumlog = sumexp + BDIM;
    float* tlog   = sumlog + BDIM;
    hipMemsetAsync(d_ws, 0, 3 * BDIM * sizeof(float), stream);

    const size_t bfoff = 65536;
    const size_t xcount = (size_t)BDIM * HDIM;
    const size_t wcount = (size_t)VDIM * HDIM;
    const size_t need = bfoff + xcount + wcount;   // fp8: 1 B/elem

    dim3 grid(BDIM / 128, VDIM / 128);
    if (ws_size >= need) {
        uint8_t* xq = (uint8_t*)d_ws + bfoff;
        uint8_t* wq = xq + xcount;
        int nx4 = (int)(xcount / 4);
        int ntot4 = (int)((xcount + wcount) / 4);
        cvt_fp8_kernel<<<4096, 256, 0, stream>>>(x, W, xq, wq, nx4, ntot4);
        gemm_reduce_fp8<<<grid, 256, 0, stream>>>(xq, wq, y, sumexp, sumlog, tlog);
    } else {
        gemm_reduce_f32<<<grid, 256, 0, stream>>>(x, W, y, sumexp, sumlog, tlog);
    }
    finalize_kernel<<<1, 256, 0, stream>>>(sumexp, sumlog, tlog, y, out);
}

// Round 10
// 788.014 us; speedup vs baseline: 1.1026x; 1.1026x over previous
//
#include <hip/hip_runtime.h>
#include <stdint.h>

#define BDIM 4096
#define HDIM 2048
#define VDIM 32000
#define HALF (BDIM / 2)
#define IGNORE_INDEX (-100)

typedef int   v8i  __attribute__((ext_vector_type(8)));
typedef int   v4i  __attribute__((ext_vector_type(4)));
typedef float v16f __attribute__((ext_vector_type(16)));
typedef float f32x4 __attribute__((ext_vector_type(4)));
typedef __bf16 bf16x8 __attribute__((ext_vector_type(8)));

#define AS1 __attribute__((address_space(1)))
#define AS3 __attribute__((address_space(3)))

__device__ __forceinline__ unsigned short f2bf(float f) {
    union { float f; unsigned int u; } v; v.f = f;
    unsigned int u = v.u;
    unsigned int r = u + 0x7FFFu + ((u >> 16) & 1u);
    return (unsigned short)(r >> 16);
}

// fp32 -> fp8(e4m3, OCP). ROUND-9: split into two branch-free, loop-free
// kernels (the old single kernel had a grid-stride loop + per-iteration
// pointer-select branch and "other" time stayed ~350us across two rewrites
// — this version is the arithmetic-floor form: 4 independent wave-contiguous
// float4 loads, straight-line VALU, 4 wave-contiguous dword stores).
// Wave wv covers chunks [wv*256, wv*256+256): lane l takes wv*256+l+{0,64,128,192}.
//
// x: scale 1. W: pre-scale by 64 (W ~ U(+-0.022) is subnormal in e4m3);
// the GEMM epilogue multiplies accumulators by 2^-6 (exact).

__device__ __forceinline__ void cvt4_store(const float4* __restrict__ s,
                                           unsigned* __restrict__ d,
                                           int j, float m) {
    float4 f0 = s[j];
    float4 f1 = s[j + 64];
    float4 f2 = s[j + 128];
    float4 f3 = s[j + 192];
    int w;
    w = __builtin_amdgcn_cvt_pk_fp8_f32(f0.x * m, f0.y * m, 0, false);
    w = __builtin_amdgcn_cvt_pk_fp8_f32(f0.z * m, f0.w * m, w, true);
    d[j] = (unsigned)w;
    w = __builtin_amdgcn_cvt_pk_fp8_f32(f1.x * m, f1.y * m, 0, false);
    w = __builtin_amdgcn_cvt_pk_fp8_f32(f1.z * m, f1.w * m, w, true);
    d[j + 64] = (unsigned)w;
    w = __builtin_amdgcn_cvt_pk_fp8_f32(f2.x * m, f2.y * m, 0, false);
    w = __builtin_amdgcn_cvt_pk_fp8_f32(f2.z * m, f2.w * m, w, true);
    d[j + 128] = (unsigned)w;
    w = __builtin_amdgcn_cvt_pk_fp8_f32(f3.x * m, f3.y * m, 0, false);
    w = __builtin_amdgcn_cvt_pk_fp8_f32(f3.z * m, f3.w * m, w, true);
    d[j + 192] = (unsigned)w;
}

// x: 4096*2048 = 8,388,608 floats = 2,097,152 float4 chunks = 2048 blocks * 1024.
__global__ __launch_bounds__(256) void cvt_x_kernel(const float* __restrict__ x,
                                                    uint8_t* __restrict__ xq) {
    const int t = blockIdx.x * 256 + threadIdx.x;
    const int j = ((t >> 6) << 8) + (t & 63);
    cvt4_store((const float4*)x, (unsigned*)xq, j, 1.0f);
}

// W: 32000*2048 = 65,536,000 floats = 16,384,000 chunks = 16000 blocks * 1024.
__global__ __launch_bounds__(256) void cvt_w_kernel(const float* __restrict__ W,
                                                    uint8_t* __restrict__ wq) {
    const int t = blockIdx.x * 256 + threadIdx.x;
    const int j = ((t >> 6) << 8) + (t & 63);
    cvt4_store((const float4*)W, (unsigned*)wq, j, 64.0f);
}

// Fused fp8 GEMM (x @ W^T) + per-row {sum exp, sum, target-logit}.
// REVERTED VERBATIM to the round-7 schedule (measured 448 us, MfmaUtil 26).
// Round-8's manual 2-phase (raw s_barrier + counted vmcnt + sched_barrier)
// REGRESSED: 536 us, MfmaUtil 21.6, WRITE_SIZE 64->380 MB (scratch/codegen
// pathology from pinning the scheduler). Do not reintroduce without fixing
// the write-traffic signature.
//
// 128x128 tile, BK=128 (two 64-wide k-slices per barrier-pair), 4 waves each
// owning a 64x64 quadrant as 2x2 tiles of mfma_scale_f32_32x32x64_f8f6f4
// (fp8 fmt, identity e8m0 scales 0x7F).
//
// Per 64-wide k-slice, LDS rows are 64 B (=64 fp8). 16-B chunk c of row r is
// stored at position sigma_r(c) = (c + ((r>>1)&3)) & 3 [2-bit row swizzle].
// Read slot for a b128 = 16*(r&1) + 4*sigma_r(c): over any aligned 8-lane
// group, (fr&1, (fr>>1)&3) enumerates all 8 four-bank slots -> conflict-free.
// Staging keeps global_load_lds's contiguous lane*16 LDS mapping and permutes
// the GLOBAL source chunk instead (all 4 chunks lie in one 64 B line).
__global__ __launch_bounds__(256, 4)
void gemm_reduce_fp8(const uint8_t* __restrict__ A, const uint8_t* __restrict__ B,
                     const int* __restrict__ y,
                     float* __restrict__ sumexp, float* __restrict__ sumlog,
                     float* __restrict__ tlog) {
    __shared__ uint8_t sA[2][128 * 64];
    __shared__ uint8_t sB[2][128 * 64];

    const int tid = threadIdx.x;
    const int lane = tid & 63;
    const int wave = tid >> 6;
    const int wm = wave >> 1, wn = wave & 1;
    const int m0 = blockIdx.x * 128;
    const int v0 = blockIdx.y * 128;

    v16f acc[2][2];
#pragma unroll
    for (int i = 0; i < 2; i++)
#pragma unroll
        for (int j = 0; j < 2; j++)
#pragma unroll
            for (int r = 0; r < 16; r++) acc[i][j][r] = 0.f;

    // Staging: wave stages rows [wave*32, wave*32+32) of sA and sB, 16 rows
    // per global_load_lds (64 lanes x 16 B). Lane l -> LDS row (l>>2), chunk
    // position p = l&3; source chunk c = (p - ((R>>1)&3)) & 3. With
    // R = wave*32 (+16) + (l>>2), (R>>1)&3 = (l>>3)&3 for both row halves.
    const int srow = wave * 32 + (lane >> 2);
    const int sc   = ((lane & 3) - ((lane >> 3) & 3)) & 3;
    const uint8_t* gA0 = A + (size_t)(m0 + srow) * HDIM + sc * 16;
    const uint8_t* gB0 = B + (size_t)(v0 + srow) * HDIM + sc * 16;
    const uint8_t* gA1 = gA0 + (size_t)16 * HDIM;
    const uint8_t* gB1 = gB0 + (size_t)16 * HDIM;
    const int lofs0 = (wave * 32) * 64;
    const int lofs1 = lofs0 + 16 * 64;

    // Fragment reads (per lane): row l&31 of the 32-row tile, k-half h=l>>5
    // -> source chunks 2h, 2h+1 at swizzled positions.
    const int fr32 = lane & 31;
    const int h = lane >> 5;
    const int swr = (fr32 >> 1) & 3;
    const int pos0 = (2 * h + swr) & 3;
    const int pos1 = (2 * h + 1 + swr) & 3;
    const int rA0 = (wm * 64 + fr32) * 64;
    const int rA1 = (wm * 64 + 32 + fr32) * 64;
    const int rB0 = (wn * 64 + fr32) * 64;
    const int rB1 = (wn * 64 + 32 + fr32) * 64;

    for (int kt = 0; kt < HDIM; kt += 128) {
        // Stage both 64-wide k-slices: slice 0 -> sA[0]/sB[0], slice 1 (+64 B
        // in the same global row) -> sA[1]/sB[1]. 8 global_load_lds total.
        __builtin_amdgcn_global_load_lds((const AS1 unsigned int*)(gA0 + kt),
                                         (AS3 unsigned int*)&sA[0][lofs0], 16, 0, 0);
        __builtin_amdgcn_global_load_lds((const AS1 unsigned int*)(gA1 + kt),
                                         (AS3 unsigned int*)&sA[0][lofs1], 16, 0, 0);
        __builtin_amdgcn_global_load_lds((const AS1 unsigned int*)(gA0 + kt + 64),
                                         (AS3 unsigned int*)&sA[1][lofs0], 16, 0, 0);
        __builtin_amdgcn_global_load_lds((const AS1 unsigned int*)(gA1 + kt + 64),
                                         (AS3 unsigned int*)&sA[1][lofs1], 16, 0, 0);
        __builtin_amdgcn_global_load_lds((const AS1 unsigned int*)(gB0 + kt),
                                         (AS3 unsigned int*)&sB[0][lofs0], 16, 0, 0);
        __builtin_amdgcn_global_load_lds((const AS1 unsigned int*)(gB1 + kt),
                                         (AS3 unsigned int*)&sB[0][lofs1], 16, 0, 0);
        __builtin_amdgcn_global_load_lds((const AS1 unsigned int*)(gB0 + kt + 64),
                                         (AS3 unsigned int*)&sB[1][lofs0], 16, 0, 0);
        __builtin_amdgcn_global_load_lds((const AS1 unsigned int*)(gB1 + kt + 64),
                                         (AS3 unsigned int*)&sB[1][lofs1], 16, 0, 0);
        __syncthreads();

#pragma unroll
        for (int s = 0; s < 2; s++) {
            const v4i* pA0 = (const v4i*)&sA[s][rA0];
            const v4i* pA1 = (const v4i*)&sA[s][rA1];
            const v4i* pB0 = (const v4i*)&sB[s][rB0];
            const v4i* pB1 = (const v4i*)&sB[s][rB1];
            v4i a00 = pA0[pos0], a01 = pA0[pos1];
            v4i a10 = pA1[pos0], a11 = pA1[pos1];
            v4i b00 = pB0[pos0], b01 = pB0[pos1];
            v4i b10 = pB1[pos0], b11 = pB1[pos1];
            v8i af0 = {a00[0], a00[1], a00[2], a00[3], a01[0], a01[1], a01[2], a01[3]};
            v8i af1 = {a10[0], a10[1], a10[2], a10[3], a11[0], a11[1], a11[2], a11[3]};
            v8i bf0 = {b00[0], b00[1], b00[2], b00[3], b01[0], b01[1], b01[2], b01[3]};
            v8i bf1 = {b10[0], b10[1], b10[2], b10[3], b11[0], b11[1], b11[2], b11[3]};

            acc[0][0] = __builtin_amdgcn_mfma_scale_f32_32x32x64_f8f6f4(
                af0, bf0, acc[0][0], 0, 0, 0, 0x7F7F7F7F, 0, 0x7F7F7F7F);
            acc[0][1] = __builtin_amdgcn_mfma_scale_f32_32x32x64_f8f6f4(
                af0, bf1, acc[0][1], 0, 0, 0, 0x7F7F7F7F, 0, 0x7F7F7F7F);
            acc[1][0] = __builtin_amdgcn_mfma_scale_f32_32x32x64_f8f6f4(
                af1, bf0, acc[1][0], 0, 0, 0, 0x7F7F7F7F, 0, 0x7F7F7F7F);
            acc[1][1] = __builtin_amdgcn_mfma_scale_f32_32x32x64_f8f6f4(
                af1, bf1, acc[1][1], 0, 0, 0, 0x7F7F7F7F, 0, 0x7F7F7F7F);
        }
        __syncthreads();
    }

    // Epilogue. 32x32 C/D layout: col = lane&31, row = (reg&3)+8*(reg>>2)+4*h.
    // Undo the W x64 pre-scale (exact).
    const float s64 = 0.015625f;
#pragma unroll
    for (int mi = 0; mi < 2; mi++) {
        const int baseRow = m0 + wm * 64 + mi * 32;
#pragma unroll
        for (int reg = 0; reg < 16; reg++) {
            float va = acc[mi][0][reg] * s64;
            float vb = acc[mi][1][reg] * s64;
            float e = __expf(va) + __expf(vb);
            float sm = va + vb;
#pragma unroll
            for (int off = 1; off < 32; off <<= 1) {
                e  += __shfl_xor(e, off);
                sm += __shfl_xor(sm, off);
            }
            int row = baseRow + (reg & 3) + 8 * (reg >> 2) + 4 * h;
            if (fr32 == 0) {
                atomicAdd(&sumexp[row], e);
                atomicAdd(&sumlog[row], sm);
            }
            int yv = y[row];
            int c0 = v0 + wn * 64 + fr32;
            if (c0 == yv) tlog[row] = va;
            if (c0 + 32 == yv) tlog[row] = vb;
        }
    }
}

// Fallback (small ws): fp32 inputs, in-kernel bf16 convert, 16x16x32 path.
__global__ __launch_bounds__(256, 4)
void gemm_reduce_f32(const float* __restrict__ A, const float* __restrict__ B,
                     const int* __restrict__ y,
                     float* __restrict__ sumexp, float* __restrict__ sumlog,
                     float* __restrict__ tlog) {
    __shared__ unsigned short sA[128 * 32];
    __shared__ unsigned short sB[128 * 32];

    const int tid  = threadIdx.x;
    const int lane = tid & 63;
    const int wave = tid >> 6;
    const int wm = wave >> 1, wn = wave & 1;
    const int m0 = blockIdx.x * 128;
    const int v0 = blockIdx.y * 128;
    const int fr = lane & 15;
    const int fq = lane >> 4;
    const int swz = (fr >> 1) & 3;

    f32x4 acc[4][4];
#pragma unroll
    for (int i = 0; i < 4; i++)
#pragma unroll
        for (int j = 0; j < 4; j++) acc[i][j] = (f32x4){0.f, 0.f, 0.f, 0.f};

    const int r8 = tid >> 3;
    const int kc = (tid & 7) * 4;
    for (int kt = 0; kt < HDIM; kt += 32) {
#pragma unroll
        for (int p = 0; p < 4; p++) {
            int row = p * 32 + r8;
            int pos = ((kc >> 3) ^ ((row >> 1) & 3)) * 8 + (kc & 7);
            float4 fa = *(const float4*)&A[(size_t)(m0 + row) * HDIM + kt + kc];
            float4 fb = *(const float4*)&B[(size_t)(v0 + row) * HDIM + kt + kc];
            ushort4 ua, ub;
            ua.x = f2bf(fa.x); ua.y = f2bf(fa.y); ua.z = f2bf(fa.z); ua.w = f2bf(fa.w);
            ub.x = f2bf(fb.x); ub.y = f2bf(fb.y); ub.z = f2bf(fb.z); ub.w = f2bf(fb.w);
            *(ushort4*)&sA[row * 32 + pos] = ua;
            *(ushort4*)&sB[row * 32 + pos] = ub;
        }
        __syncthreads();

        bf16x8 af[4], bf[4];
#pragma unroll
        for (int i = 0; i < 4; i++) {
            af[i] = *(const bf16x8*)&sA[(wm * 64 + i * 16 + fr) * 32 + (fq ^ swz) * 8];
            bf[i] = *(const bf16x8*)&sB[(wn * 64 + i * 16 + fr) * 32 + (fq ^ swz) * 8];
        }
#pragma unroll
        for (int mi = 0; mi < 4; mi++)
#pragma unroll
            for (int ni = 0; ni < 4; ni++)
                acc[mi][ni] = __builtin_amdgcn_mfma_f32_16x16x32_bf16(
                    af[mi], bf[ni], acc[mi][ni], 0, 0, 0);
        __syncthreads();
    }

    const int baseRow = m0 + wm * 64;
    const int cbase = v0 + wn * 64 + fr;
#pragma unroll
    for (int mi = 0; mi < 4; mi++) {
        float se[4] = {0.f, 0.f, 0.f, 0.f};
        float sl[4] = {0.f, 0.f, 0.f, 0.f};
#pragma unroll
        for (int ni = 0; ni < 4; ni++)
#pragma unroll
            for (int r = 0; r < 4; r++) {
                float v = acc[mi][ni][r];
                se[r] += __expf(v);
                sl[r] += v;
            }
#pragma unroll
        for (int r = 0; r < 4; r++) {
            float e = se[r], s = sl[r];
#pragma unroll
            for (int off = 1; off < 16; off <<= 1) {
                e += __shfl_xor(e, off);
                s += __shfl_xor(s, off);
            }
            int row = baseRow + mi * 16 + fq * 4 + r;
            if (fr == 0) {
                atomicAdd(&sumexp[row], e);
                atomicAdd(&sumlog[row], s);
            }
            int yv = y[row];
#pragma unroll
            for (int ni = 0; ni < 4; ni++)
                if (cbase + ni * 16 == yv) tlog[row] = acc[mi][ni][r];
        }
    }
}

// Final scalar loss from per-row stats. One block.
__global__ void finalize_kernel(const float* __restrict__ sumexp,
                                const float* __restrict__ sumlog,
                                const float* __restrict__ tlog,
                                const int* __restrict__ y,
                                float* __restrict__ out) {
    __shared__ float red[3][4];
    float s_nll = 0.f, s_or = 0.f, cnt = 0.f;
    for (int p = threadIdx.x; p < HALF; p += blockDim.x) {
        float lse_c = logf(sumexp[p]);
        float lse_r = logf(sumexp[p + HALF]);
        float mc = sumlog[p] * (1.0f / VDIM);
        float mr = sumlog[p + HALF] * (1.0f / VDIM);
        int yv = y[p];
        if (yv != IGNORE_INDEX) { s_nll += lse_c - tlog[p]; cnt += 1.f; }
        float ch = mc - lse_c, rj = mr - lse_r;
        float lo = (ch - rj) - (log1pf(-expf(ch)) - log1pf(-expf(rj)));
        float ls = fminf(lo, 0.f) - log1pf(expf(-fabsf(lo)));
        s_or += 0.1f * ls;
    }
    for (int off = 32; off; off >>= 1) {
        s_nll += __shfl_down(s_nll, off);
        s_or  += __shfl_down(s_or, off);
        cnt   += __shfl_down(cnt, off);
    }
    int wave = threadIdx.x >> 6, lane = threadIdx.x & 63;
    if (lane == 0) { red[0][wave] = s_nll; red[1][wave] = s_or; red[2][wave] = cnt; }
    __syncthreads();
    if (threadIdx.x == 0) {
        float tn = 0.f, to = 0.f, tc = 0.f;
        for (int w = 0; w < 4; w++) { tn += red[0][w]; to += red[1][w]; tc += red[2][w]; }
        out[0] = tn / fmaxf(tc, 1.f) - to / (float)HALF;
    }
}

extern "C" void kernel_launch(void* const* d_in, const int* in_sizes, int n_in,
                              void* d_out, int out_size, void* d_ws, size_t ws_size,
                              hipStream_t stream) {
    const float* x = (const float*)d_in[0];
    const float* W = (const float*)d_in[1];
    const int* y   = (const int*)d_in[2];
    float* out     = (float*)d_out;

    float* sumexp = (float*)d_ws;
    float* sumlog = sumexp + BDIM;
    float* tlog   = sumlog + BDIM;
    hipMemsetAsync(d_ws, 0, 3 * BDIM * sizeof(float), stream);

    const size_t bfoff = 65536;
    const size_t xcount = (size_t)BDIM * HDIM;
    const size_t wcount = (size_t)VDIM * HDIM;
    const size_t need = bfoff + xcount + wcount;   // fp8: 1 B/elem

    dim3 grid(BDIM / 128, VDIM / 128);
    if (ws_size >= need) {
        uint8_t* xq = (uint8_t*)d_ws + bfoff;
        uint8_t* wq = xq + xcount;
        // x: 2,097,152 float4 chunks / 1024 per block = 2048 blocks.
        // W: 16,384,000 float4 chunks / 1024 per block = 16000 blocks.
        cvt_x_kernel<<<2048, 256, 0, stream>>>(x, xq);
        cvt_w_kernel<<<16000, 256, 0, stream>>>(W, wq);
        gemm_reduce_fp8<<<grid, 256, 0, stream>>>(xq, wq, y, sumexp, sumlog, tlog);
    } else {
        gemm_reduce_f32<<<grid, 256, 0, stream>>>(x, W, y, sumexp, sumlog, tlog);
    }
    finalize_kernel<<<1, 256, 0, stream>>>(sumexp, sumlog, tlog, y, out);
}